// Round 1
// baseline (211.642 us; speedup 1.0000x reference)
//
#include <hip/hip_runtime.h>
#include <math.h>

// Problem constants (from reference): regular (3,6) QC-LDPC, rate 1/2.
#define B_     128
#define N_     24576
#define M_     12288
#define E_     73728
#define NCOMP_ 4096      // graph decomposes into 4096 independent components
#define ITERS_ 10
#define CLIP_  20.0f

// Structure proof: edge_to_cn = e/6, edge_to_vn = e%N. CN c owns edges [6c,6c+6).
// For c = k, k+4096, k+8192 those edges map to VNs {6k..6k+5} exactly.
// => component k: CNs {k, k+4096, k+8192}, VNs {6k..6k+5}, 18 edges; fully
// independent of all other components -> whole decode fits in one thread's regs.

__device__ __forceinline__ float clipf(float x) {
    return fminf(fmaxf(x, -CLIP_), CLIP_);
}

__global__ __launch_bounds__(256) void ldpc_fused_kernel(
    const float* __restrict__ llr_in,     // [B, N]
    const float* __restrict__ cn_weight,  // [ITERS]
    const float* __restrict__ ch_weight,  // [ITERS]
    const float* __restrict__ cn_bias,    // [ITERS]
    float* __restrict__ out,              // [0]=loss (written by finalize), [1..]=dec [B,N]
    double* __restrict__ loss_acc)        // d_ws scratch, pre-zeroed
{
    const int gid = blockIdx.x * 256 + threadIdx.x;
    const int b = gid >> 12;              // / NCOMP_
    const int k = gid & (NCOMP_ - 1);

    // 6 contiguous channel LLRs for this component (8B-aligned: offset = 24k floats)
    const float2* p2 = (const float2*)(llr_in + b * N_ + 6 * k);
    float2 t0 = p2[0], t1 = p2[1], t2 = p2[2];
    float llr[6] = {t0.x, t0.y, t1.x, t1.y, t2.x, t2.y};

    float c2v[3][6];
    float sum[6];
#pragma unroll
    for (int i = 0; i < 6; ++i) {
        sum[i] = 0.f;
        c2v[0][i] = 0.f; c2v[1][i] = 0.f; c2v[2][i] = 0.f;
    }

    float local_loss = 0.f;

#pragma unroll 1   // keep body compact; weights are uniform scalar loads per iter
    for (int it = 0; it < ITERS_; ++it) {
        const float cw   = ch_weight[it];
        const float cnw  = cn_weight[it];
        const float bias = cn_bias[it];

        // VN total (shared by all 3 CNs): w_ch + sum_llr
        float u[6];
#pragma unroll
        for (int i = 0; i < 6; ++i) u[i] = llr[i] * cw + sum[i];

#pragma unroll
        for (int cn = 0; cn < 3; ++cn) {
            float a[6];
            unsigned neg[6];
            unsigned par = 0;
#pragma unroll
            for (int j = 0; j < 6; ++j) {
                float t = clipf(u[j] - c2v[cn][j]);   // quantized v2c
                a[j] = fabsf(t);
                unsigned n = (t < 0.f) ? 1u : 0u;
                neg[j] = n;
                par ^= n;
            }
            // two smallest magnitudes + argmin. Equivalent to reference's
            // m1/m2/cnt form incl. ties: duplicate min => m2 == m1.
            float m1 = a[0], m2 = 1e30f;
            int am = 0;
#pragma unroll
            for (int j = 1; j < 6; ++j) {
                if (a[j] < m1)      { m2 = m1; m1 = a[j]; am = j; }
                else if (a[j] < m2) { m2 = a[j]; }
            }
#pragma unroll
            for (int j = 0; j < 6; ++j) {
                float ext  = (j == am) ? m2 : m1;     // extrinsic min, >= 0
                float mag0 = ext * cnw;               // * cn_weight[it]
                unsigned s = par ^ neg[j];            // sign_tot * sign_e  (==-1 iff s)
                float c2vw = s ? -mag0 : mag0;
                float mag  = fmaxf(fabsf(c2vw) - bias, 0.f);  // offset min-sum
                c2v[cn][j] = clipf(copysignf(mag, c2vw));     // quantize
            }
        }

        // marginal + loss (same add order as the reference scatter: e, e+N, e+2N)
#pragma unroll
        for (int i = 0; i < 6; ++i) {
            sum[i] = (c2v[0][i] + c2v[1][i]) + c2v[2][i];
            float dec = llr[i] + sum[i];
            float x = -dec;                                   // softplus(-dec), stable
            local_loss += fmaxf(x, 0.f) + log1pf(expf(-fabsf(x)));
        }
    }

    // final dec
    float* outd = out + 1 + b * N_ + 6 * k;
#pragma unroll
    for (int i = 0; i < 6; ++i) outd[i] = llr[i] + sum[i];

    // loss reduction: wave64 shuffle -> LDS across 4 waves -> 1 atomic per block
#pragma unroll
    for (int off = 32; off > 0; off >>= 1)
        local_loss += __shfl_down(local_loss, off);
    __shared__ float wsum[4];
    const int lane = threadIdx.x & 63;
    const int wid  = threadIdx.x >> 6;
    if (lane == 0) wsum[wid] = local_loss;
    __syncthreads();
    if (threadIdx.x == 0) {
        double t = (double)wsum[0] + (double)wsum[1] + (double)wsum[2] + (double)wsum[3];
        atomicAdd(loss_acc, t);
    }
}

__global__ void ldpc_finalize_kernel(const double* __restrict__ loss_acc,
                                     float* __restrict__ out)
{
    // loss = sum_it mean_it = grand_total / (B*N)
    out[0] = (float)(loss_acc[0] * (1.0 / ((double)B_ * (double)N_)));
}

extern "C" void kernel_launch(void* const* d_in, const int* in_sizes, int n_in,
                              void* d_out, int out_size, void* d_ws, size_t ws_size,
                              hipStream_t stream) {
    const float* llr_in    = (const float*)d_in[0];
    const float* cn_weight = (const float*)d_in[1];
    const float* ch_weight = (const float*)d_in[2];
    const float* cn_bias   = (const float*)d_in[3];
    // d_in[4] (edge_to_vn) and d_in[5] (edge_to_cn) are not needed: the graph
    // structure is closed-form (e%N, e/6) and hardcoded in the component map.

    float*  out = (float*)d_out;
    double* acc = (double*)d_ws;

    hipMemsetAsync(d_ws, 0, sizeof(double), stream);   // graph-capture-safe memset node

    const int total  = B_ * NCOMP_;                    // 524288 threads
    ldpc_fused_kernel<<<total / 256, 256, 0, stream>>>(
        llr_in, cn_weight, ch_weight, cn_bias, out, acc);
    ldpc_finalize_kernel<<<1, 1, 0, stream>>>(acc, out);
}

// Round 2
// 154.550 us; speedup vs baseline: 1.3694x; 1.3694x over previous
//
#include <hip/hip_runtime.h>
#include <math.h>

// Regular (3,6) QC-LDPC, rate 1/2 (constants from reference).
#define B_     128
#define N_     24576
#define NCOMP_ 4096      // graph decomposes into 4096 independent components
#define ITERS_ 10
#define CLIP_  20.0f
#define NBLOCKS_ ((B_ * NCOMP_) / 256)

// Structure proof: edge_to_cn = e/6, edge_to_vn = e%N. CN c owns edges [6c,6c+6).
// For c = k, k+4096, k+8192 those edges map to VNs {6k..6k+5} exactly.
// => component k: CNs {k, k+4096, k+8192}, VNs {6k..6k+5}, 18 edges; fully
// independent of all other components -> whole decode fits in one thread's regs.

__device__ __forceinline__ float clipf(float x) {
    return fminf(fmaxf(x, -CLIP_), CLIP_);   // compiler emits v_med3_f32
}

__global__ __launch_bounds__(256) void ldpc_fused_kernel(
    const float* __restrict__ llr_in,     // [B, N]
    const float* __restrict__ cn_weight,  // [ITERS]
    const float* __restrict__ ch_weight,  // [ITERS]
    const float* __restrict__ cn_bias,    // [ITERS]
    float* __restrict__ out,              // [0]=loss, [1..]=dec [B,N]
    double* __restrict__ loss_acc,        // d_ws+0, pre-zeroed
    unsigned* __restrict__ done_ctr)      // d_ws+8, pre-zeroed
{
    const int gid = blockIdx.x * 256 + threadIdx.x;
    const int b = gid >> 12;              // / NCOMP_
    const int k = gid & (NCOMP_ - 1);

    // 6 contiguous channel LLRs for this component (8B-aligned: offset = 24k B)
    const float2* p2 = (const float2*)(llr_in + b * N_ + 6 * k);
    float2 t0 = p2[0], t1 = p2[1], t2 = p2[2];
    float llr[6] = {t0.x, t0.y, t1.x, t1.y, t2.x, t2.y};

    float c2v[3][6];
    float sum[6];
#pragma unroll
    for (int i = 0; i < 6; ++i) {
        sum[i] = 0.f;
        c2v[0][i] = 0.f; c2v[1][i] = 0.f; c2v[2][i] = 0.f;
    }

    float local_loss = 0.f;

#pragma unroll 1
    for (int it = 0; it < ITERS_; ++it) {
        const float cw    = ch_weight[it];
        const float cnw   = cn_weight[it];
        const float nbias = -cn_bias[it];
        const float cnw_a = fabsf(cnw);
        const unsigned cnw_s = __float_as_uint(cnw) & 0x80000000u;

        // VN totals (shared by the 3 CNs of this component)
        float u6[6];
#pragma unroll
        for (int i = 0; i < 6; ++i) u6[i] = fmaf(llr[i], cw, sum[i]);

#pragma unroll
        for (int cn = 0; cn < 3; ++cn) {
            // v2c = clip(u - c2v); track sign bits + magnitudes
            unsigned tb[6];
            float a[6];
            unsigned par = cnw_s;          // fold cn_weight sign into parity
#pragma unroll
            for (int j = 0; j < 6; ++j) {
                float t = clipf(u6[j] - c2v[cn][j]);
                unsigned tu = __float_as_uint(t);
                tb[j] = tu;
                par ^= tu;                 // sign-bit parity (lower bits ignored)
                a[j] = fabsf(t);
            }
            // branch-free two-min: m1=min, m2=second-min (ties => m2==m1,
            // which makes the (a==m1)?m2:m1 select bit-exact vs the
            // reference's m1/m2/cnt formulation)
            float m1 = a[0], m2 = 1e30f;
#pragma unroll
            for (int j = 1; j < 6; ++j) {
                float mx = fmaxf(a[j], m1);
                m1 = fminf(m1, a[j]);
                m2 = fminf(m2, mx);
            }
#pragma unroll
            for (int j = 0; j < 6; ++j) {
                float ext = (a[j] == m1) ? m2 : m1;           // extrinsic min >=0
                float mag = fmaxf(fmaf(ext, cnw_a, nbias), 0.f); // offset min-sum
                mag = fminf(mag, CLIP_);                       // quantize (mag>=0)
                unsigned sgn = (par ^ tb[j]) & 0x80000000u;    // sign_tot*sign_e*sign(cnw)
                c2v[cn][j] = __uint_as_float(sgn | __float_as_uint(mag));
            }
        }

        // marginals + decision + loss (add order matches reference scatter)
#pragma unroll
        for (int i = 0; i < 6; ++i) {
            sum[i] = (c2v[0][i] + c2v[1][i]) + c2v[2][i];
            float dec = llr[i] + sum[i];
            // softplus(-dec) = max(-dec,0) + log(1+exp(-|dec|)), fast intrinsics
            local_loss += fmaxf(-dec, 0.f) + __logf(1.f + __expf(-fabsf(dec)));
        }
    }

    // final dec
    float* outd = out + 1 + b * N_ + 6 * k;
#pragma unroll
    for (int i = 0; i < 6; ++i) outd[i] = llr[i] + sum[i];

    // loss reduction: wave64 shuffle -> LDS across 4 waves -> 1 atomic per block
#pragma unroll
    for (int off = 32; off > 0; off >>= 1)
        local_loss += __shfl_down(local_loss, off);
    __shared__ float wsum[4];
    const int lane = threadIdx.x & 63;
    const int wid  = threadIdx.x >> 6;
    if (lane == 0) wsum[wid] = local_loss;
    __syncthreads();
    if (threadIdx.x == 0) {
        double t = (double)wsum[0] + (double)wsum[1] + (double)wsum[2] + (double)wsum[3];
        atomicAdd(loss_acc, t);
        __threadfence();                          // order acc-add before ctr-add
        unsigned prev = atomicAdd(done_ctr, 1u);
        if (prev == NBLOCKS_ - 1) {               // last block finalizes the loss
            double total = atomicAdd(loss_acc, 0.0);  // coherent read
            out[0] = (float)(total * (1.0 / ((double)B_ * (double)N_)));
        }
    }
}

extern "C" void kernel_launch(void* const* d_in, const int* in_sizes, int n_in,
                              void* d_out, int out_size, void* d_ws, size_t ws_size,
                              hipStream_t stream) {
    const float* llr_in    = (const float*)d_in[0];
    const float* cn_weight = (const float*)d_in[1];
    const float* ch_weight = (const float*)d_in[2];
    const float* cn_bias   = (const float*)d_in[3];
    // d_in[4]/d_in[5] (edge maps) unused: structure is closed-form (e%N, e/6).

    float*    out = (float*)d_out;
    double*   acc = (double*)d_ws;
    unsigned* ctr = (unsigned*)((char*)d_ws + 8);

    hipMemsetAsync(d_ws, 0, 16, stream);  // zero acc + counter (capture-safe node)

    ldpc_fused_kernel<<<NBLOCKS_, 256, 0, stream>>>(
        llr_in, cn_weight, ch_weight, cn_bias, out, acc, ctr);
}

// Round 3
// 149.492 us; speedup vs baseline: 1.4157x; 1.0338x over previous
//
#include <hip/hip_runtime.h>
#include <math.h>

// Regular (3,6) QC-LDPC, rate 1/2 (constants from reference).
#define B_     128
#define N_     24576
#define NCOMP_ 4096      // graph decomposes into 4096 independent components
#define ITERS_ 10
#define CLIP_  20.0f
#define NBLOCKS_ ((B_ * NCOMP_) / 256)

// Structure proof: edge_to_cn = e/6, edge_to_vn = e%N. CN c owns edges [6c,6c+6).
// For c = k, k+4096, k+8192 those edges map to VNs {6k..6k+5} exactly.
// => component k: CNs {k, k+4096, k+8192}, VNs {6k..6k+5}, 18 edges; fully
// independent of all other components -> whole decode fits in one thread's regs.

__device__ __forceinline__ float clipf(float x) {
    return fminf(fmaxf(x, -CLIP_), CLIP_);   // v_med3_f32
}
__device__ __forceinline__ float clamp0c(float x) {
    return fminf(fmaxf(x, 0.f), CLIP_);      // v_med3_f32 (relu + clip for mag>=0)
}

__global__ __launch_bounds__(256, 8) void ldpc_fused_kernel(
    const float* __restrict__ llr_in,     // [B, N]
    const float* __restrict__ cn_weight,  // [ITERS]
    const float* __restrict__ ch_weight,  // [ITERS]
    const float* __restrict__ cn_bias,    // [ITERS]
    float* __restrict__ out,              // [0]=loss, [1..]=dec [B,N]
    double* __restrict__ loss_acc,        // d_ws+0, pre-zeroed
    unsigned* __restrict__ done_ctr)      // d_ws+8, pre-zeroed
{
    const int gid = blockIdx.x * 256 + threadIdx.x;
    const int b = gid >> 12;              // / NCOMP_
    const int k = gid & (NCOMP_ - 1);

    // Preload ALL per-iteration weights up front (uniform -> SGPRs, one stall).
    float cwv[ITERS_], cnwa[ITERS_], nbias[ITERS_];
    unsigned cnws[ITERS_];
#pragma unroll
    for (int i = 0; i < ITERS_; ++i) {
        float w = cn_weight[i];
        cwv[i]   = ch_weight[i];
        cnwa[i]  = fabsf(w);
        cnws[i]  = __float_as_uint(w) & 0x80000000u;
        nbias[i] = -cn_bias[i];
    }

    // 6 contiguous channel LLRs for this component (8B-aligned: offset = 24k B)
    const float2* p2 = (const float2*)(llr_in + b * N_ + 6 * k);
    float2 t0 = p2[0], t1 = p2[1], t2 = p2[2];
    float llr[6] = {t0.x, t0.y, t1.x, t1.y, t2.x, t2.y};

    float c2v[3][6];
    float sum[6];
#pragma unroll
    for (int i = 0; i < 6; ++i) {
        sum[i] = 0.f;
        c2v[0][i] = 0.f; c2v[1][i] = 0.f; c2v[2][i] = 0.f;
    }

    float accMax = 0.f;   // sum of max(-dec,0) terms
    float accLog = 0.f;   // sum of log(1+exp(-|dec|)) terms

#pragma unroll
    for (int it = 0; it < ITERS_; ++it) {
        const float cw = cwv[it];

        // VN totals (shared by the 3 CNs of this component)
        float u6[6];
#pragma unroll
        for (int i = 0; i < 6; ++i) u6[i] = fmaf(llr[i], cw, sum[i]);

#pragma unroll
        for (int cn = 0; cn < 3; ++cn) {
            // v2c = clip(u - c2v); keep raw bits for sign bookkeeping
            float t[6];
            unsigned tb[6];
            unsigned par = cnws[it];       // fold cn_weight sign into parity
#pragma unroll
            for (int j = 0; j < 6; ++j) {
                float v = clipf(u6[j] - c2v[cn][j]);
                t[j] = v;
                tb[j] = __float_as_uint(v);
                par ^= tb[j];              // only bit31 meaningful (masked later)
            }
            // branch-free two-min over |t[j]| (abs folded as input modifiers).
            // Ties: duplicate min => m2 == m1 => select below is bit-exact vs
            // the reference's m1/m2/cnt formulation.
            float a0 = fabsf(t[0]), a1 = fabsf(t[1]);
            float m1 = fminf(a0, a1);
            float m2 = fmaxf(a0, a1);
#pragma unroll
            for (int j = 2; j < 6; ++j) {
                float a = fabsf(t[j]);
                float mx = fmaxf(a, m1);
                m1 = fminf(m1, a);
                m2 = fminf(m2, mx);
            }
            // Only two possible output magnitudes per CN -> precompute both:
            // clamp(relu(m * |cnw| - bias), CLIP) == med3(fma(..), 0, CLIP)
            float M1p = clamp0c(fmaf(m1, cnwa[it], nbias[it]));
            float M2p = clamp0c(fmaf(m2, cnwa[it], nbias[it]));
#pragma unroll
            for (int j = 0; j < 6; ++j) {
                float ext = (fabsf(t[j]) == m1) ? M2p : M1p;  // extrinsic mag
                unsigned sgn = par ^ tb[j];                   // sign of others
                c2v[cn][j] = __uint_as_float((sgn & 0x80000000u)
                                             | __float_as_uint(ext)); // v_and_or
            }
        }

        // marginals + decision + loss (add order matches reference scatter)
#pragma unroll
        for (int i = 0; i < 6; ++i) {
            sum[i] = (c2v[0][i] + c2v[1][i]) + c2v[2][i];
            float dec = llr[i] + sum[i];
            // softplus(-dec) = max(-dec,0) + log(1+exp(-|dec|))
            accMax += fmaxf(-dec, 0.f);
            accLog += __logf(1.f + __expf(-fabsf(dec)));
        }
    }

    // final dec
    float* outd = out + 1 + b * N_ + 6 * k;
#pragma unroll
    for (int i = 0; i < 6; ++i) outd[i] = llr[i] + sum[i];

    // loss reduction: wave64 shuffle -> LDS across 4 waves -> 1 atomic per block
    float local_loss = accMax + accLog;
#pragma unroll
    for (int off = 32; off > 0; off >>= 1)
        local_loss += __shfl_down(local_loss, off);
    __shared__ float wsum[4];
    const int lane = threadIdx.x & 63;
    const int wid  = threadIdx.x >> 6;
    if (lane == 0) wsum[wid] = local_loss;
    __syncthreads();
    if (threadIdx.x == 0) {
        double t = (double)wsum[0] + (double)wsum[1] + (double)wsum[2] + (double)wsum[3];
        atomicAdd(loss_acc, t);
        __threadfence();                          // order acc-add before ctr-add
        unsigned prev = atomicAdd(done_ctr, 1u);
        if (prev == NBLOCKS_ - 1) {               // last block finalizes the loss
            double total = atomicAdd(loss_acc, 0.0);  // coherent read
            out[0] = (float)(total * (1.0 / ((double)B_ * (double)N_)));
        }
    }
}

extern "C" void kernel_launch(void* const* d_in, const int* in_sizes, int n_in,
                              void* d_out, int out_size, void* d_ws, size_t ws_size,
                              hipStream_t stream) {
    const float* llr_in    = (const float*)d_in[0];
    const float* cn_weight = (const float*)d_in[1];
    const float* ch_weight = (const float*)d_in[2];
    const float* cn_bias   = (const float*)d_in[3];
    // d_in[4]/d_in[5] (edge maps) unused: structure is closed-form (e%N, e/6).

    float*    out = (float*)d_out;
    double*   acc = (double*)d_ws;
    unsigned* ctr = (unsigned*)((char*)d_ws + 8);

    hipMemsetAsync(d_ws, 0, 16, stream);  // zero acc + counter (capture-safe node)

    ldpc_fused_kernel<<<NBLOCKS_, 256, 0, stream>>>(
        llr_in, cn_weight, ch_weight, cn_bias, out, acc, ctr);
}

// Round 4
// 102.140 us; speedup vs baseline: 2.0721x; 1.4636x over previous
//
#include <hip/hip_runtime.h>
#include <math.h>

// Regular (3,6) QC-LDPC, rate 1/2 (constants from reference).
#define B_     128
#define N_     24576
#define NCOMP_ 4096      // graph decomposes into 4096 independent components
#define ITERS_ 10
#define CLIP_  20.0f
#define NBLOCKS_ ((B_ * NCOMP_) / 256)   // 2048

// Structure proof: edge_to_cn = e/6, edge_to_vn = e%N. CN c owns edges [6c,6c+6).
// For c = k, k+4096, k+8192 those edges map to VNs {6k..6k+5} exactly.
// => component k: CNs {k, k+4096, k+8192}, VNs {6k..6k+5}, 18 edges; fully
// independent of all other components -> whole decode fits in one thread's regs.

__device__ __forceinline__ float clipf(float x) {
    return fminf(fmaxf(x, -CLIP_), CLIP_);   // v_med3_f32
}
__device__ __forceinline__ float clamp0c(float x) {
    return fminf(fmaxf(x, 0.f), CLIP_);      // v_med3_f32 (relu + clip, mag>=0)
}

// NOTE (R3 lesson): __launch_bounds__(256,8) capped VGPR at 64 -> full-unroll
// state spilled to scratch (VGPR_Count=16, +4MB HBM writes). (256,4) = 128-VGPR
// cap keeps everything in registers; 4 waves/SIMD is ample for a VALU kernel.
__global__ __launch_bounds__(256, 4) void ldpc_fused_kernel(
    const float* __restrict__ llr_in,     // [B, N]
    const float* __restrict__ cn_weight,  // [ITERS]
    const float* __restrict__ ch_weight,  // [ITERS]
    const float* __restrict__ cn_bias,    // [ITERS]
    float* __restrict__ out,              // [0]=loss (finalize), [1..]=dec [B,N]
    double* __restrict__ partials)        // d_ws: one slot per block, no atomics
{
    const int gid = blockIdx.x * 256 + threadIdx.x;
    const int b = gid >> 12;              // / NCOMP_
    const int k = gid & (NCOMP_ - 1);

    // Per-iteration weights: uniform scalar loads, constant-indexed after unroll.
    float cwv[ITERS_], cnwa[ITERS_], nbias[ITERS_];
    unsigned cnws[ITERS_];
#pragma unroll
    for (int i = 0; i < ITERS_; ++i) {
        float w = cn_weight[i];
        cwv[i]   = ch_weight[i];
        cnwa[i]  = fabsf(w);
        cnws[i]  = __float_as_uint(w) & 0x80000000u;
        nbias[i] = -cn_bias[i];
    }

    // 6 contiguous channel LLRs for this component (8B-aligned: offset = 24k B)
    const float2* p2 = (const float2*)(llr_in + b * N_ + 6 * k);
    float2 t0 = p2[0], t1 = p2[1], t2 = p2[2];
    float llr[6] = {t0.x, t0.y, t1.x, t1.y, t2.x, t2.y};

    float c2v[3][6];
    float sum[6];
#pragma unroll
    for (int i = 0; i < 6; ++i) {
        sum[i] = 0.f;
        c2v[0][i] = 0.f; c2v[1][i] = 0.f; c2v[2][i] = 0.f;
    }

    float accMax = 0.f;   // sum of max(-dec,0) terms
    float accLog = 0.f;   // sum of log(1+exp(-|dec|)) terms

#pragma unroll
    for (int it = 0; it < ITERS_; ++it) {
        const float cw = cwv[it];

        // VN totals (shared by the 3 CNs of this component)
        float u6[6];
#pragma unroll
        for (int i = 0; i < 6; ++i) u6[i] = fmaf(llr[i], cw, sum[i]);

#pragma unroll
        for (int cn = 0; cn < 3; ++cn) {
            // v2c = clip(u - c2v); keep raw bits for sign bookkeeping
            float t[6];
            unsigned tb[6];
            unsigned par = cnws[it];       // fold cn_weight sign into parity
#pragma unroll
            for (int j = 0; j < 6; ++j) {
                float v = clipf(u6[j] - c2v[cn][j]);
                t[j] = v;
                tb[j] = __float_as_uint(v);
                par ^= tb[j];              // only bit31 meaningful (masked later)
            }
            // branch-free two-min over |t[j]| (abs folded as input modifiers).
            // Ties: duplicate min => m2 == m1 => the select below is bit-exact
            // vs the reference's m1/m2/cnt formulation.
            float a0 = fabsf(t[0]), a1 = fabsf(t[1]);
            float m1 = fminf(a0, a1);
            float m2 = fmaxf(a0, a1);
#pragma unroll
            for (int j = 2; j < 6; ++j) {
                float a = fabsf(t[j]);
                float mx = fmaxf(a, m1);
                m1 = fminf(m1, a);
                m2 = fminf(m2, mx);
            }
            // Only two possible output magnitudes per CN -> precompute both:
            float M1p = clamp0c(fmaf(m1, cnwa[it], nbias[it]));
            float M2p = clamp0c(fmaf(m2, cnwa[it], nbias[it]));
#pragma unroll
            for (int j = 0; j < 6; ++j) {
                float ext = (fabsf(t[j]) == m1) ? M2p : M1p;  // extrinsic mag
                unsigned sgn = par ^ tb[j];                   // sign of others
                c2v[cn][j] = __uint_as_float((sgn & 0x80000000u)
                                             | __float_as_uint(ext)); // v_and_or
            }
        }

        // marginals + decision + loss (add order matches reference scatter)
#pragma unroll
        for (int i = 0; i < 6; ++i) {
            sum[i] = (c2v[0][i] + c2v[1][i]) + c2v[2][i];
            float dec = llr[i] + sum[i];
            // softplus(-dec) = max(-dec,0) + log(1+exp(-|dec|))
            accMax += fmaxf(-dec, 0.f);
            accLog += __logf(1.f + __expf(-fabsf(dec)));
        }
    }

    // final dec (3 x 8B stores; wave writes 1536 contiguous bytes)
    float2* outd = (float2*)(out + 1 + b * N_ + 6 * k);
    outd[0] = make_float2(llr[0] + sum[0], llr[1] + sum[1]);
    outd[1] = make_float2(llr[2] + sum[2], llr[3] + sum[3]);
    outd[2] = make_float2(llr[4] + sum[4], llr[5] + sum[5]);

    // loss: wave64 shuffle -> LDS -> ONE PLAIN STORE per block (no atomics!).
    // R2/R3 were pinned at ~105us by 4096 serialized same-address device-scope
    // RMWs draining after compute (grid fully resident -> nothing overlaps it).
    float local_loss = accMax + accLog;
#pragma unroll
    for (int off = 32; off > 0; off >>= 1)
        local_loss += __shfl_down(local_loss, off);
    __shared__ float wsum[4];
    const int lane = threadIdx.x & 63;
    const int wid  = threadIdx.x >> 6;
    if (lane == 0) wsum[wid] = local_loss;
    __syncthreads();
    if (threadIdx.x == 0) {
        double t = ((double)wsum[0] + (double)wsum[1])
                 + ((double)wsum[2] + (double)wsum[3]);
        partials[blockIdx.x] = t;      // distinct address per block
    }
}

__global__ __launch_bounds__(256) void ldpc_finalize_kernel(
    const double* __restrict__ partials,  // [NBLOCKS_]
    float* __restrict__ out)
{
    double s = 0.0;
#pragma unroll
    for (int i = 0; i < NBLOCKS_ / 256; ++i)           // 8 loads/thread
        s += partials[threadIdx.x + 256 * i];
#pragma unroll
    for (int off = 32; off > 0; off >>= 1)
        s += __shfl_down(s, off);
    __shared__ double wsum[4];
    const int lane = threadIdx.x & 63;
    const int wid  = threadIdx.x >> 6;
    if (lane == 0) wsum[wid] = s;
    __syncthreads();
    if (threadIdx.x == 0) {
        double total = (wsum[0] + wsum[1]) + (wsum[2] + wsum[3]);
        out[0] = (float)(total * (1.0 / ((double)B_ * (double)N_)));
    }
}

extern "C" void kernel_launch(void* const* d_in, const int* in_sizes, int n_in,
                              void* d_out, int out_size, void* d_ws, size_t ws_size,
                              hipStream_t stream) {
    const float* llr_in    = (const float*)d_in[0];
    const float* cn_weight = (const float*)d_in[1];
    const float* ch_weight = (const float*)d_in[2];
    const float* cn_bias   = (const float*)d_in[3];
    // d_in[4]/d_in[5] (edge maps) unused: structure is closed-form (e%N, e/6).

    float*  out      = (float*)d_out;
    double* partials = (double*)d_ws;     // 2048 doubles = 16 KB, all overwritten

    ldpc_fused_kernel<<<NBLOCKS_, 256, 0, stream>>>(
        llr_in, cn_weight, ch_weight, cn_bias, out, partials);
    ldpc_finalize_kernel<<<1, 256, 0, stream>>>(partials, out);
}

// Round 5
// 89.934 us; speedup vs baseline: 2.3533x; 1.1357x over previous
//
#include <hip/hip_runtime.h>
#include <math.h>

// Regular (3,6) QC-LDPC, rate 1/2 (constants from reference).
#define B_     128
#define N_     24576
#define NCOMP_ 4096      // graph decomposes into 4096 independent components
#define ITERS_ 10
#define CLIP_  20.0f
#define NBLOCKS_ ((B_ * NCOMP_) / 256)   // 2048

// Structure proof: edge_to_cn = e/6, edge_to_vn = e%N. CN c owns edges [6c,6c+6).
// For c = k, k+4096, k+8192 those edges map to VNs {6k..6k+5} exactly.
// => component k: CNs {k, k+4096, k+8192}, VNs {6k..6k+5}, 18 edges; fully
// independent of all other components -> whole decode fits in one thread's regs.

__device__ __forceinline__ float clipf(float x) {
    return fminf(fmaxf(x, -CLIP_), CLIP_);   // v_med3_f32
}
__device__ __forceinline__ float clamp0c(float x) {
    return fminf(fmaxf(x, 0.f), CLIP_);      // v_med3_f32 (relu + clip, mag>=0)
}
__device__ __forceinline__ float fmin3(float a, float b, float c) {
    return fminf(fminf(a, b), c);            // v_min3_f32
}
__device__ __forceinline__ float fmed3(float a, float b, float c) {
    return __builtin_amdgcn_fmed3f(a, b, c); // v_med3_f32
}
// Force a wave-uniform value into an SGPR (weights: 30 scalars otherwise
// squatting in VGPRs for the whole kernel).
__device__ __forceinline__ float rfl(float x) {
    return __uint_as_float(__builtin_amdgcn_readfirstlane(__float_as_uint(x)));
}

// R3 lesson: (256,8) => 64-VGPR cap => spill (+4MB scratch HBM traffic).
// (256,6) => 85-VGPR cap; persistent state (llr6+c2v18+sum6+accs) + transients
// fits comfortably once weights are in SGPRs.
__global__ __launch_bounds__(256, 6) void ldpc_fused_kernel(
    const float* __restrict__ llr_in,     // [B, N]
    const float* __restrict__ cn_weight,  // [ITERS]
    const float* __restrict__ ch_weight,  // [ITERS]
    const float* __restrict__ cn_bias,    // [ITERS]
    float* __restrict__ out,              // [0]=loss (finalize), [1..]=dec [B,N]
    double* __restrict__ partials)        // d_ws: one slot per block, no atomics
{
    const int gid = blockIdx.x * 256 + threadIdx.x;
    const int b = gid >> 12;              // / NCOMP_
    const int k = gid & (NCOMP_ - 1);

    // Per-iteration weights -> SGPRs (uniform).
    float cwv[ITERS_], cnwa[ITERS_], nbias[ITERS_];
    unsigned cnws[ITERS_];
#pragma unroll
    for (int i = 0; i < ITERS_; ++i) {
        float w  = rfl(cn_weight[i]);
        cwv[i]   = rfl(ch_weight[i]);
        cnwa[i]  = fabsf(w);
        cnws[i]  = __float_as_uint(w) & 0x80000000u;
        nbias[i] = -rfl(cn_bias[i]);
    }

    // 6 contiguous channel LLRs for this component (8B-aligned: offset = 24k B)
    const float2* p2 = (const float2*)(llr_in + b * N_ + 6 * k);
    float2 t0 = p2[0], t1 = p2[1], t2 = p2[2];
    float llr[6] = {t0.x, t0.y, t1.x, t1.y, t2.x, t2.y};

    float c2v[3][6];
    float sum[6];
#pragma unroll
    for (int i = 0; i < 6; ++i) {
        sum[i] = 0.f;
        c2v[0][i] = 0.f; c2v[1][i] = 0.f; c2v[2][i] = 0.f;
    }

    float accMax  = 0.f;   // sum of max(-dec,0) terms
    float prodLog = 1.f;   // prod of (1+exp(-|dec|)); 60 terms, each in (1,2]
                           // => product <= 2^60, no overflow; ONE log at end.

#pragma unroll
    for (int it = 0; it < ITERS_; ++it) {
        const float cw = cwv[it];

        // VN totals (shared by the 3 CNs of this component)
        float u6[6];
#pragma unroll
        for (int i = 0; i < 6; ++i) u6[i] = fmaf(llr[i], cw, sum[i]);

#pragma unroll
        for (int cn = 0; cn < 3; ++cn) {
            // v2c = clip(u - c2v); sign bits tracked via float bitcasts (free)
            float t[6];
            unsigned par = cnws[it];       // fold cn_weight sign into parity
#pragma unroll
            for (int j = 0; j < 6; ++j) {
                t[j] = clipf(u6[j] - c2v[cn][j]);
                par ^= __float_as_uint(t[j]);   // only bit31 meaningful
            }
            // Two-min via sorted-triple merge (abs folded as VOP3 modifiers):
            //   m1 = min(minA, minB)
            //   m2 = min3(max(minA,minB), medA, medB)
            // Exact incl. ties: dup-min => m2 == m1, so the (a==m1)?m2:m1
            // select below is bit-exact vs the reference m1/m2/cnt form.
            float minA = fmin3(fabsf(t[0]), fabsf(t[1]), fabsf(t[2]));
            float medA = fmed3(fabsf(t[0]), fabsf(t[1]), fabsf(t[2]));
            float minB = fmin3(fabsf(t[3]), fabsf(t[4]), fabsf(t[5]));
            float medB = fmed3(fabsf(t[3]), fabsf(t[4]), fabsf(t[5]));
            float m1 = fminf(minA, minB);
            float m2 = fmin3(fmaxf(minA, minB), medA, medB);
            // Only two possible output magnitudes per CN -> precompute both:
            float M1p = clamp0c(fmaf(m1, cnwa[it], nbias[it]));
            float M2p = clamp0c(fmaf(m2, cnwa[it], nbias[it]));
#pragma unroll
            for (int j = 0; j < 6; ++j) {
                float ext = (fabsf(t[j]) == m1) ? M2p : M1p;  // extrinsic mag
                unsigned sx = par ^ __float_as_uint(t[j]);    // sign of others
                // v_bfi_b32: take bit31 from sx, rest from ext
                c2v[cn][j] = __uint_as_float((sx & 0x80000000u)
                                             | __float_as_uint(ext));
            }
        }

        // marginals + decision + loss (add order matches reference scatter)
#pragma unroll
        for (int i = 0; i < 6; ++i) {
            sum[i] = (c2v[0][i] + c2v[1][i]) + c2v[2][i];
            float dec = llr[i] + sum[i];
            // softplus(-dec) = max(-dec,0) + log(1+exp(-|dec|));
            // the log terms are accumulated as a product, one log at the end.
            accMax  += fmaxf(-dec, 0.f);
            prodLog *= 1.f + __expf(-fabsf(dec));
        }
    }

    // final dec (3 x 8B stores; wave writes 1536 contiguous bytes)
    float2* outd = (float2*)(out + 1 + b * N_ + 6 * k);
    outd[0] = make_float2(llr[0] + sum[0], llr[1] + sum[1]);
    outd[1] = make_float2(llr[2] + sum[2], llr[3] + sum[3]);
    outd[2] = make_float2(llr[4] + sum[4], llr[5] + sum[5]);

    // loss: wave64 shuffle -> LDS -> ONE PLAIN STORE per block (no atomics;
    // R2/R3 were pinned ~105us by 4096 serialized same-address RMWs).
    float local_loss = accMax + __logf(prodLog);
#pragma unroll
    for (int off = 32; off > 0; off >>= 1)
        local_loss += __shfl_down(local_loss, off);
    __shared__ float wsum[4];
    const int lane = threadIdx.x & 63;
    const int wid  = threadIdx.x >> 6;
    if (lane == 0) wsum[wid] = local_loss;
    __syncthreads();
    if (threadIdx.x == 0) {
        double t = ((double)wsum[0] + (double)wsum[1])
                 + ((double)wsum[2] + (double)wsum[3]);
        partials[blockIdx.x] = t;      // distinct address per block
    }
}

__global__ __launch_bounds__(256) void ldpc_finalize_kernel(
    const double* __restrict__ partials,  // [NBLOCKS_]
    float* __restrict__ out)
{
    double s = 0.0;
#pragma unroll
    for (int i = 0; i < NBLOCKS_ / 256; ++i)           // 8 loads/thread
        s += partials[threadIdx.x + 256 * i];
#pragma unroll
    for (int off = 32; off > 0; off >>= 1)
        s += __shfl_down(s, off);
    __shared__ double wsum[4];
    const int lane = threadIdx.x & 63;
    const int wid  = threadIdx.x >> 6;
    if (lane == 0) wsum[wid] = s;
    __syncthreads();
    if (threadIdx.x == 0) {
        double total = (wsum[0] + wsum[1]) + (wsum[2] + wsum[3]);
        out[0] = (float)(total * (1.0 / ((double)B_ * (double)N_)));
    }
}

extern "C" void kernel_launch(void* const* d_in, const int* in_sizes, int n_in,
                              void* d_out, int out_size, void* d_ws, size_t ws_size,
                              hipStream_t stream) {
    const float* llr_in    = (const float*)d_in[0];
    const float* cn_weight = (const float*)d_in[1];
    const float* ch_weight = (const float*)d_in[2];
    const float* cn_bias   = (const float*)d_in[3];
    // d_in[4]/d_in[5] (edge maps) unused: structure is closed-form (e%N, e/6).

    float*  out      = (float*)d_out;
    double* partials = (double*)d_ws;     // 2048 doubles = 16 KB, all overwritten

    ldpc_fused_kernel<<<NBLOCKS_, 256, 0, stream>>>(
        llr_in, cn_weight, ch_weight, cn_bias, out, partials);
    ldpc_finalize_kernel<<<1, 256, 0, stream>>>(partials, out);
}